// Round 14
// baseline (482.383 us; speedup 1.0000x reference)
//
#include <hip/hip_runtime.h>

static constexpr int D = 96;       // hidden size
static constexpr int G3 = 3 * D;   // 288 gate rows
static constexpr int NSTEPS = 4;   // GGNN propagation steps
static constexpr int NT = 18;      // 288/16 col-tiles per weight matrix
static constexpr int SCAN_BLK = 1024;  // elements per scan block
static constexpr int SLP = 104;    // s-tile LDS row pad (fp16)

typedef __attribute__((ext_vector_type(8))) _Float16 f16x8;  // 8 fp16 (4 VGPRs)
typedef __attribute__((ext_vector_type(4))) _Float16 f16x4;
typedef __attribute__((ext_vector_type(8))) unsigned short u16x8;
typedef __attribute__((ext_vector_type(4))) float f32x4;     // MFMA C/D frag

// A-fragment for mfma_f32_16x16x32_f16 from fp16 row-major [*,96]:
// lane holds row=r0+(lane&15), k = kc*32 + (lane>>4)*8 .. +7 -> 16B contiguous
// rows clamped to n-1 (results for clamped rows are discarded by store guard)
__device__ __forceinline__ f16x8 load_a_frag_clamp(const _Float16* __restrict__ base,
                                                   int r0, int lane, int kc, int n) {
  int row = r0 + (lane & 15);
  if (row >= n) row = n - 1;
  int k0 = kc * 32 + ((lane >> 4) << 3);
  return *(const f16x8*)(base + (size_t)row * D + k0);
}

// Swizzled B-fragment: slot (t,kc) holds 64 lanes' f16x8 contiguously (1KB)
__device__ __forceinline__ f16x8 load_b_swz(const _Float16* __restrict__ W,
                                            int t, int kc, int lane) {
  return *(const f16x8*)(W + (((size_t)t * 3 + kc) * 64 + lane) * 8);
}

// ---------- one-time prep ----------

__global__ void convert_x_kernel(const float* __restrict__ x,
                                 _Float16* __restrict__ h, int total4) {
  int i = blockIdx.x * blockDim.x + threadIdx.x;
  if (i >= total4) return;
  float4 v = ((const float4*)x)[i];
  f16x4 o;
  o[0] = (_Float16)v.x; o[1] = (_Float16)v.y;
  o[2] = (_Float16)v.z; o[3] = (_Float16)v.w;
  *(f16x4*)(h + (size_t)i * 4) = o;
}

// W_x[r][k] = sum_c W_ih[r][c] * W_e[c][k]; bxe[r] = sum_c W_ih[r][c] * b_e[c]
__global__ void compute_wx_kernel(const float* __restrict__ Wih,
                                  const float* __restrict__ We,
                                  const float* __restrict__ be,
                                  float* __restrict__ Wx,
                                  float* __restrict__ bxe) {
  int idx = blockIdx.x * blockDim.x + threadIdx.x;
  if (idx < G3 * D) {
    int r = idx / D, k = idx - r * D;
    float acc = 0.f;
    for (int c = 0; c < D; ++c) acc += Wih[r * D + c] * We[c * D + k];
    Wx[idx] = acc;
  } else if (idx < G3 * D + G3) {
    int r = idx - G3 * D;
    float acc = 0.f;
    for (int c = 0; c < D; ++c) acc += Wih[r * D + c] * be[c];
    bxe[r] = acc;
  }
}

// convert Wx/Whh to fp16 in MFMA-fragment (swizzled) order
__global__ void swizzle_f16_kernel(const float* __restrict__ Wx,
                                   const float* __restrict__ Whh,
                                   _Float16* __restrict__ WxF,
                                   _Float16* __restrict__ WhhF) {
  int idx = blockIdx.x * blockDim.x + threadIdx.x;
  if (idx >= 2 * NT * 3 * 64) return;
  int mat = idx / (NT * 3 * 64);
  int rem = idx - mat * (NT * 3 * 64);
  int t = rem / (3 * 64);
  int rem2 = rem - t * (3 * 64);
  int kc = rem2 >> 6;
  int lane = rem2 & 63;
  int c = t * 16 + (lane & 15);
  int k0 = kc * 32 + ((lane >> 4) << 3);
  const float* W = mat ? Whh : Wx;
  _Float16* dF = mat ? WhhF : WxF;
  f16x8 o;
#pragma unroll
  for (int j = 0; j < 8; ++j) o[j] = (_Float16)W[(size_t)c * D + k0 + j];
  *(f16x8*)(dF + (((size_t)t * 3 + kc) * 64 + lane) * 8) = o;
}

// ---------- CSR build ----------

__global__ void hist_kernel(const int* __restrict__ dst, int* __restrict__ counts, int E) {
  int e = blockIdx.x * blockDim.x + threadIdx.x;
  if (e < E) atomicAdd(&counts[dst[e]], 1);
}

__global__ void partial_sum_kernel(const int* __restrict__ counts,
                                   int* __restrict__ blk_sums, int n) {
  __shared__ int red[256];
  int base = blockIdx.x * SCAN_BLK;
  int tid = threadIdx.x;
  int s = 0;
#pragma unroll
  for (int j = 0; j < 4; ++j) {
    int i = base + j * 256 + tid;
    if (i < n) s += counts[i];
  }
  red[tid] = s;
  __syncthreads();
  for (int off = 128; off > 0; off >>= 1) {
    if (tid < off) red[tid] += red[tid + off];
    __syncthreads();
  }
  if (tid == 0) blk_sums[blockIdx.x] = red[0];
}

__global__ void scan_offsets_kernel(const int* __restrict__ blk_sums,
                                    int* __restrict__ blk_off,
                                    int* __restrict__ row_ptr, int nb, int n) {
  __shared__ int lds[64];
  int tid = threadIdx.x;
  if (tid < nb) lds[tid] = blk_sums[tid];
  __syncthreads();
  if (tid == 0) {
    int run = 0;
    for (int i = 0; i < nb; ++i) { blk_off[i] = run; run += lds[i]; }
    row_ptr[n] = run;
  }
}

__global__ void block_scan_kernel(const int* __restrict__ counts,
                                  const int* __restrict__ blk_off,
                                  int* __restrict__ row_ptr, int n) {
  __shared__ int red[256];
  int base = blockIdx.x * SCAN_BLK;
  int tid = threadIdx.x;
  int i0 = base + tid * 4;
  int v0 = 0, v1 = 0, v2 = 0, v3 = 0;
  if (i0 + 3 < n) {
    int4 c = *(const int4*)(counts + i0);
    v0 = c.x; v1 = c.y; v2 = c.z; v3 = c.w;
  } else {
    if (i0 < n) v0 = counts[i0];
    if (i0 + 1 < n) v1 = counts[i0 + 1];
    if (i0 + 2 < n) v2 = counts[i0 + 2];
  }
  int tsum = v0 + v1 + v2 + v3;
  red[tid] = tsum;
  __syncthreads();
  for (int off = 1; off < 256; off <<= 1) {
    int t = (tid >= off) ? red[tid - off] : 0;
    __syncthreads();
    red[tid] += t;
    __syncthreads();
  }
  int excl = blk_off[blockIdx.x] + red[tid] - tsum;
  if (i0 < n) row_ptr[i0] = excl;
  if (i0 + 1 < n) row_ptr[i0 + 1] = excl + v0;
  if (i0 + 2 < n) row_ptr[i0 + 2] = excl + v0 + v1;
  if (i0 + 3 < n) row_ptr[i0 + 3] = excl + v0 + v1 + v2;
}

// csr_src stored as uint16 (n < 65536): halves scatter-write traffic
__global__ void fill_kernel(const int* __restrict__ src, const int* __restrict__ dst,
                            const int* __restrict__ row_ptr,
                            int* __restrict__ fillc,
                            unsigned short* __restrict__ csr_src, int E) {
  int e = blockIdx.x * blockDim.x + threadIdx.x;
  if (e >= E) return;
  int t = dst[e];
  int pos = row_ptr[t] + atomicAdd(&fillc[t], 1);
  csr_src[pos] = (unsigned short)src[e];
}

// ---------- fused per-step kernel ----------

// Fused aggregate + GRU. Block = 32 rows, 6 waves (384 threads), LDS = 6.7 KB.
// Phase 1: 32 rows x 12 threads gather neighbor sums into sl; 16-deep load
//          unroll with vectorized u16 index loads (MLP = 16 outstanding/thread).
// Phase 2: wave w owns col-tile w and computes all three gates in-register;
//          h A-fragments issued BEFORE the barrier (latency hidden).
__global__ __launch_bounds__(384) void gru_fused_kernel(
    const _Float16* __restrict__ h, _Float16* __restrict__ hout,
    const int* __restrict__ row_ptr, const unsigned short* __restrict__ csr_src,
    const _Float16* __restrict__ WxF, const _Float16* __restrict__ WhhF,
    const float* __restrict__ bxe, const float* __restrict__ bih,
    const float* __restrict__ bhh, int n) {
  __shared__ _Float16 sl[32 * SLP];   // 6.7 KB aggregated s tile
  int r0 = blockIdx.x << 5;   // 32 rows per block
  int tid = threadIdx.x;
  int w = tid >> 6;
  int lane = tid & 63;

  // ---- phase 1: gather ----
  {
    int row = tid / 12;        // 0..31
    int part = tid - row * 12; // chunk of 8 fp16
    int grow = r0 + row;
    float acc[8];
#pragma unroll
    for (int j = 0; j < 8; ++j) acc[j] = 0.f;
    if (grow < n) {
      int beg = row_ptr[grow], end = row_ptr[grow + 1];
      const _Float16* hp = h + (size_t)part * 8;
      int e = beg;
      // peel to even e so u16x8 index loads are 4B-aligned
      if ((e & 1) && e < end) {
        f16x8 v = *(const f16x8*)(hp + (size_t)csr_src[e] * D);
#pragma unroll
        for (int j = 0; j < 8; ++j) acc[j] += (float)v[j];
        ++e;
      }
      for (; e + 15 < end; e += 16) {
        u16x8 i0 = *(const u16x8*)(csr_src + e);
        u16x8 i1 = *(const u16x8*)(csr_src + e + 8);
        f16x8 v0 = *(const f16x8*)(hp + (size_t)i0[0] * D);
        f16x8 v1 = *(const f16x8*)(hp + (size_t)i0[1] * D);
        f16x8 v2 = *(const f16x8*)(hp + (size_t)i0[2] * D);
        f16x8 v3 = *(const f16x8*)(hp + (size_t)i0[3] * D);
        f16x8 v4 = *(const f16x8*)(hp + (size_t)i0[4] * D);
        f16x8 v5 = *(const f16x8*)(hp + (size_t)i0[5] * D);
        f16x8 v6 = *(const f16x8*)(hp + (size_t)i0[6] * D);
        f16x8 v7 = *(const f16x8*)(hp + (size_t)i0[7] * D);
        f16x8 u0 = *(const f16x8*)(hp + (size_t)i1[0] * D);
        f16x8 u1 = *(const f16x8*)(hp + (size_t)i1[1] * D);
        f16x8 u2 = *(const f16x8*)(hp + (size_t)i1[2] * D);
        f16x8 u3 = *(const f16x8*)(hp + (size_t)i1[3] * D);
        f16x8 u4 = *(const f16x8*)(hp + (size_t)i1[4] * D);
        f16x8 u5 = *(const f16x8*)(hp + (size_t)i1[5] * D);
        f16x8 u6 = *(const f16x8*)(hp + (size_t)i1[6] * D);
        f16x8 u7 = *(const f16x8*)(hp + (size_t)i1[7] * D);
#pragma unroll
        for (int j = 0; j < 8; ++j) {
          float s0 = (((float)v0[j] + (float)v1[j]) + ((float)v2[j] + (float)v3[j])) +
                     (((float)v4[j] + (float)v5[j]) + ((float)v6[j] + (float)v7[j]));
          float s1 = (((float)u0[j] + (float)u1[j]) + ((float)u2[j] + (float)u3[j])) +
                     (((float)u4[j] + (float)u5[j]) + ((float)u6[j] + (float)u7[j]));
          acc[j] += s0 + s1;
        }
      }
      if (e + 7 < end) {
        u16x8 i0 = *(const u16x8*)(csr_src + e);
        f16x8 v0 = *(const f16x8*)(hp + (size_t)i0[0] * D);
        f16x8 v1 = *(const f16x8*)(hp + (size_t)i0[1] * D);
        f16x8 v2 = *(const f16x8*)(hp + (size_t)i0[2] * D);
        f16x8 v3 = *(const f16x8*)(hp + (size_t)i0[3] * D);
        f16x8 v4 = *(const f16x8*)(hp + (size_t)i0[4] * D);
        f16x8 v5 = *(const f16x8*)(hp + (size_t)i0[5] * D);
        f16x8 v6 = *(const f16x8*)(hp + (size_t)i0[6] * D);
        f16x8 v7 = *(const f16x8*)(hp + (size_t)i0[7] * D);
#pragma unroll
        for (int j = 0; j < 8; ++j)
          acc[j] += (((float)v0[j] + (float)v1[j]) + ((float)v2[j] + (float)v3[j])) +
                    (((float)v4[j] + (float)v5[j]) + ((float)v6[j] + (float)v7[j]));
        e += 8;
      }
      for (; e < end; ++e) {
        f16x8 v = *(const f16x8*)(hp + (size_t)csr_src[e] * D);
#pragma unroll
        for (int j = 0; j < 8; ++j) acc[j] += (float)v[j];
      }
    }
    f16x8 o;
#pragma unroll
    for (int j = 0; j < 8; ++j) o[j] = (_Float16)acc[j];
    *(f16x8*)&sl[row * SLP + part * 8] = o;
  }

  // hoist h A-fragments above the barrier (independent of sl)
  f16x8 aH0[3], aH1[3];
#pragma unroll
  for (int kc = 0; kc < 3; ++kc) {
    aH0[kc] = load_a_frag_clamp(h, r0, lane, kc, n);
    aH1[kc] = load_a_frag_clamp(h, r0 + 16, lane, kc, n);
  }
  __syncthreads();

  // ---- phase 2: per-wave col-tile GRU (all gates in-register) ----
  const int t = w;                 // col-tile 0..5
  const int col_l = lane & 15;
  const int rq = (lane >> 4) << 2;
  const int col = t * 16 + col_l;

  const float br  = bih[col] + bhh[col];
  const float bz  = bih[D + col] + bhh[D + col];
  const float bxn = bih[2 * D + col];
  const float bhn = bhh[2 * D + col];
  const float xr = bxe[col], xz = bxe[D + col], xnc = bxe[2 * D + col];

#pragma unroll
  for (int rt = 0; rt < 2; ++rt) {
    const int rbase = r0 + rt * 16;
    f16x8 aS[3];
#pragma unroll
    for (int kc = 0; kc < 3; ++kc) {
      int k0 = kc * 32 + ((lane >> 4) << 3);
      aS[kc] = *(const f16x8*)&sl[(rt * 16 + (lane & 15)) * SLP + k0];
    }
    const f16x8* aH = rt ? aH1 : aH0;
    f32x4 accR = {0.f, 0.f, 0.f, 0.f};
    f32x4 accZ = {0.f, 0.f, 0.f, 0.f};
    f32x4 accXN = {0.f, 0.f, 0.f, 0.f};
    f32x4 accHN = {0.f, 0.f, 0.f, 0.f};
#pragma unroll
    for (int kc = 0; kc < 3; ++kc) {
      accR  = __builtin_amdgcn_mfma_f32_16x16x32_f16(aS[kc], load_b_swz(WxF,  t,      kc, lane), accR, 0, 0, 0);
      accR  = __builtin_amdgcn_mfma_f32_16x16x32_f16(aH[kc], load_b_swz(WhhF, t,      kc, lane), accR, 0, 0, 0);
      accZ  = __builtin_amdgcn_mfma_f32_16x16x32_f16(aS[kc], load_b_swz(WxF,  6 + t,  kc, lane), accZ, 0, 0, 0);
      accZ  = __builtin_amdgcn_mfma_f32_16x16x32_f16(aH[kc], load_b_swz(WhhF, 6 + t,  kc, lane), accZ, 0, 0, 0);
      accXN = __builtin_amdgcn_mfma_f32_16x16x32_f16(aS[kc], load_b_swz(WxF,  12 + t, kc, lane), accXN, 0, 0, 0);
      accHN = __builtin_amdgcn_mfma_f32_16x16x32_f16(aH[kc], load_b_swz(WhhF, 12 + t, kc, lane), accHN, 0, 0, 0);
    }
#pragma unroll
    for (int q = 0; q < 4; ++q) {
      int grow = rbase + rq + q;
      if (grow < n) {
        float degf = (float)(row_ptr[grow + 1] - row_ptr[grow]);
        float rg = 1.0f / (1.0f + __expf(-(accR[q] + br + degf * xr)));
        float zg = 1.0f / (1.0f + __expf(-(accZ[q] + bz + degf * xz)));
        float ng = tanhf(accXN[q] + bxn + degf * xnc + rg * (accHN[q] + bhn));
        float hv = (float)h[(size_t)grow * D + col];
        hout[(size_t)grow * D + col] = (_Float16)((1.0f - zg) * ng + zg * hv);
      }
    }
  }
}

// logits[i,c] = sum_k elu(h[i,k]) * Wfc[c,k] + bfc[c]
__global__ void head_kernel(const _Float16* __restrict__ h,
                            const float* __restrict__ Wfc,
                            const float* __restrict__ bfc,
                            float* __restrict__ out,
                            int n, int C) {
  int idx = blockIdx.x * blockDim.x + threadIdx.x;
  if (idx >= n * C) return;
  int i = idx / C;
  int c = idx - i * C;
  const _Float16* hr = h + (size_t)i * D;
  const float* wr = Wfc + (size_t)c * D;
  float acc = bfc[c];
#pragma unroll 8
  for (int k = 0; k < D; ++k) {
    float hv = (float)hr[k];
    float e = hv > 0.0f ? hv : (__expf(hv) - 1.0f);
    acc += e * wr[k];
  }
  out[idx] = acc;
}

extern "C" void kernel_launch(void* const* d_in, const int* in_sizes, int n_in,
                              void* d_out, int out_size, void* d_ws, size_t ws_size,
                              hipStream_t stream) {
  const float* x    = (const float*)d_in[0];
  const int*   src  = (const int*)d_in[1];
  const int*   dst  = (const int*)d_in[2];
  const float* W_e  = (const float*)d_in[3];
  const float* b_e  = (const float*)d_in[4];
  const float* W_ih = (const float*)d_in[5];
  const float* W_hh = (const float*)d_in[6];
  const float* b_ih = (const float*)d_in[7];
  const float* b_hh = (const float*)d_in[8];
  const float* W_fc = (const float*)d_in[9];
  const float* b_fc = (const float*)d_in[10];

  const int n = in_sizes[0] / D;   // 50000
  const int E = in_sizes[1];       // 800000
  const int C = out_size / n;      // 10

  // ws layout (fp16 state):
  _Float16* hA = (_Float16*)d_ws;                 // n*D fp16
  _Float16* hB = hA + (size_t)n * D;              // n*D fp16
  float* Wx    = (float*)(hB + (size_t)n * D);    // G3*D fp32 temp
  _Float16* WxF  = (_Float16*)(Wx + (size_t)G3 * D);  // G3*D fp16 swizzled
  _Float16* WhhF = WxF + (size_t)G3 * D;
  float* bxe   = (float*)(WhhF + (size_t)G3 * D); // G3 fp32
  int* counts  = (int*)(bxe + G3);                // n
  int* fillc   = counts + n;                      // n
  int* row_ptr = fillc + n;                       // n+1
  unsigned short* csr_src = (unsigned short*)(row_ptr + (n + 1));  // E u16
  int* blk_sums = (int*)(csr_src + E);            // <=64  (E even -> aligned)
  int* blk_off  = blk_sums + 64;                  // <=64

  const int threads = 256;
  const int nb = (n + SCAN_BLK - 1) / SCAN_BLK;

  (void)hipMemsetAsync(counts, 0, (size_t)2 * n * sizeof(int), stream);
  hist_kernel<<<(E + threads - 1) / threads, threads, 0, stream>>>(dst, counts, E);
  partial_sum_kernel<<<nb, 256, 0, stream>>>(counts, blk_sums, n);
  scan_offsets_kernel<<<1, 64, 0, stream>>>(blk_sums, blk_off, row_ptr, nb, n);
  block_scan_kernel<<<nb, 256, 0, stream>>>(counts, blk_off, row_ptr, n);
  fill_kernel<<<(E + threads - 1) / threads, threads, 0, stream>>>(src, dst, row_ptr,
                                                                   fillc, csr_src, E);
  compute_wx_kernel<<<(G3 * D + G3 + threads - 1) / threads, threads, 0, stream>>>(
      W_ih, W_e, b_e, Wx, bxe);
  swizzle_f16_kernel<<<(2 * NT * 3 * 64 + threads - 1) / threads, threads, 0, stream>>>(
      Wx, W_hh, WxF, WhhF);
  convert_x_kernel<<<((n * D / 4) + threads - 1) / threads, threads, 0, stream>>>(
      x, hA, n * D / 4);

  const int gridG = (n + 31) / 32;   // 32 rows per block

  const _Float16* hcur = hA;
  _Float16* hnext = hB;
  for (int step = 0; step < NSTEPS; ++step) {
    gru_fused_kernel<<<gridG, 384, 0, stream>>>(hcur, hnext, row_ptr, csr_src,
                                                WxF, WhhF, bxe, b_ih, b_hh, n);
    const _Float16* t = hcur; hcur = hnext; hnext = (_Float16*)t;
  }

  const int gridH = (n * C + threads - 1) / threads;
  head_kernel<<<gridH, threads, 0, stream>>>(hcur, W_fc, b_fc, (float*)d_out, n, C);
}

// Round 15
// 342.212 us; speedup vs baseline: 1.4096x; 1.4096x over previous
//
#include <hip/hip_runtime.h>

static constexpr int D = 96;       // hidden size
static constexpr int G3 = 3 * D;   // 288 gate rows
static constexpr int NSTEPS = 4;   // GGNN propagation steps
static constexpr int NT = 18;      // 288/16 col-tiles per weight matrix
static constexpr int SCAN_BLK = 1024;  // elements per scan block
static constexpr int SLP = 104;    // s-tile LDS row pad (fp16)
static constexpr int PLS = 97;     // plane row stride (dwords)
static constexpr int PLANE = 16 * PLS;

typedef __attribute__((ext_vector_type(8))) _Float16 f16x8;  // 8 fp16 (4 VGPRs)
typedef __attribute__((ext_vector_type(4))) _Float16 f16x4;
typedef __attribute__((ext_vector_type(4))) float f32x4;     // MFMA C/D frag

// A-fragment for mfma_f32_16x16x32_f16 from fp16 row-major [*,96]
__device__ __forceinline__ f16x8 load_a_frag(const _Float16* __restrict__ base,
                                             int r0, int lane, int kc) {
  int row = r0 + (lane & 15);
  int k0 = kc * 32 + ((lane >> 4) << 3);
  return *(const f16x8*)(base + (size_t)row * D + k0);
}

// Swizzled B-fragment: slot (t,kc) holds 64 lanes' f16x8 contiguously (1KB)
__device__ __forceinline__ f16x8 load_b_swz(const _Float16* __restrict__ W,
                                            int t, int kc, int lane) {
  return *(const f16x8*)(W + (((size_t)t * 3 + kc) * 64 + lane) * 8);
}

// ---------- one-time prep ----------

__global__ void convert_x_kernel(const float* __restrict__ x,
                                 _Float16* __restrict__ h, int total4) {
  int i = blockIdx.x * blockDim.x + threadIdx.x;
  if (i >= total4) return;
  float4 v = ((const float4*)x)[i];
  f16x4 o;
  o[0] = (_Float16)v.x; o[1] = (_Float16)v.y;
  o[2] = (_Float16)v.z; o[3] = (_Float16)v.w;
  *(f16x4*)(h + (size_t)i * 4) = o;
}

// W_x[r][k] = sum_c W_ih[r][c] * W_e[c][k]; bxe[r] = sum_c W_ih[r][c] * b_e[c]
__global__ void compute_wx_kernel(const float* __restrict__ Wih,
                                  const float* __restrict__ We,
                                  const float* __restrict__ be,
                                  float* __restrict__ Wx,
                                  float* __restrict__ bxe) {
  int idx = blockIdx.x * blockDim.x + threadIdx.x;
  if (idx < G3 * D) {
    int r = idx / D, k = idx - r * D;
    float acc = 0.f;
    for (int c = 0; c < D; ++c) acc += Wih[r * D + c] * We[c * D + k];
    Wx[idx] = acc;
  } else if (idx < G3 * D + G3) {
    int r = idx - G3 * D;
    float acc = 0.f;
    for (int c = 0; c < D; ++c) acc += Wih[r * D + c] * be[c];
    bxe[r] = acc;
  }
}

// convert Wx/Whh to fp16 in MFMA-fragment (swizzled) order
__global__ void swizzle_f16_kernel(const float* __restrict__ Wx,
                                   const float* __restrict__ Whh,
                                   _Float16* __restrict__ WxF,
                                   _Float16* __restrict__ WhhF) {
  int idx = blockIdx.x * blockDim.x + threadIdx.x;
  if (idx >= 2 * NT * 3 * 64) return;
  int mat = idx / (NT * 3 * 64);
  int rem = idx - mat * (NT * 3 * 64);
  int t = rem / (3 * 64);
  int rem2 = rem - t * (3 * 64);
  int kc = rem2 >> 6;
  int lane = rem2 & 63;
  int c = t * 16 + (lane & 15);
  int k0 = kc * 32 + ((lane >> 4) << 3);
  const float* W = mat ? Whh : Wx;
  _Float16* dF = mat ? WhhF : WxF;
  f16x8 o;
#pragma unroll
  for (int j = 0; j < 8; ++j) o[j] = (_Float16)W[(size_t)c * D + k0 + j];
  *(f16x8*)(dF + (((size_t)t * 3 + kc) * 64 + lane) * 8) = o;
}

// ---------- CSR build ----------

__global__ void hist_kernel(const int* __restrict__ dst, int* __restrict__ counts, int E) {
  int e = blockIdx.x * blockDim.x + threadIdx.x;
  if (e < E) atomicAdd(&counts[dst[e]], 1);
}

__global__ void partial_sum_kernel(const int* __restrict__ counts,
                                   int* __restrict__ blk_sums, int n) {
  __shared__ int red[256];
  int base = blockIdx.x * SCAN_BLK;
  int tid = threadIdx.x;
  int s = 0;
#pragma unroll
  for (int j = 0; j < 4; ++j) {
    int i = base + j * 256 + tid;
    if (i < n) s += counts[i];
  }
  red[tid] = s;
  __syncthreads();
  for (int off = 128; off > 0; off >>= 1) {
    if (tid < off) red[tid] += red[tid + off];
    __syncthreads();
  }
  if (tid == 0) blk_sums[blockIdx.x] = red[0];
}

__global__ void scan_offsets_kernel(const int* __restrict__ blk_sums,
                                    int* __restrict__ blk_off,
                                    int* __restrict__ row_ptr, int nb, int n) {
  __shared__ int lds[64];
  int tid = threadIdx.x;
  if (tid < nb) lds[tid] = blk_sums[tid];
  __syncthreads();
  if (tid == 0) {
    int run = 0;
    for (int i = 0; i < nb; ++i) { blk_off[i] = run; run += lds[i]; }
    row_ptr[n] = run;
  }
}

__global__ void block_scan_kernel(const int* __restrict__ counts,
                                  const int* __restrict__ blk_off,
                                  int* __restrict__ row_ptr, int n) {
  __shared__ int red[256];
  int base = blockIdx.x * SCAN_BLK;
  int tid = threadIdx.x;
  int i0 = base + tid * 4;
  int v0 = 0, v1 = 0, v2 = 0, v3 = 0;
  if (i0 + 3 < n) {
    int4 c = *(const int4*)(counts + i0);
    v0 = c.x; v1 = c.y; v2 = c.z; v3 = c.w;
  } else {
    if (i0 < n) v0 = counts[i0];
    if (i0 + 1 < n) v1 = counts[i0 + 1];
    if (i0 + 2 < n) v2 = counts[i0 + 2];
  }
  int tsum = v0 + v1 + v2 + v3;
  red[tid] = tsum;
  __syncthreads();
  for (int off = 1; off < 256; off <<= 1) {
    int t = (tid >= off) ? red[tid - off] : 0;
    __syncthreads();
    red[tid] += t;
    __syncthreads();
  }
  int excl = blk_off[blockIdx.x] + red[tid] - tsum;
  if (i0 < n) row_ptr[i0] = excl;
  if (i0 + 1 < n) row_ptr[i0 + 1] = excl + v0;
  if (i0 + 2 < n) row_ptr[i0 + 2] = excl + v0 + v1;
  if (i0 + 3 < n) row_ptr[i0 + 3] = excl + v0 + v1 + v2;
}

// Phase A of two-level fill: route edges into per-bucket staging runs.
// Bucket b = dst>>10; staging region for b = [row_ptr[b<<10], row_ptr[(b+1)<<10])
// (extents are exactly the bucket's edge count). Each block LDS-counts its 1024
// edges, claims one contiguous range per bucket (1 atomic), writes runs.
__global__ void route_kernel(const int* __restrict__ src, const int* __restrict__ dst,
                             const int* __restrict__ row_ptr,
                             int* __restrict__ bucket_fill,
                             unsigned* __restrict__ stage, int E, int n) {
  __shared__ int cnt[64], gbase[64], rpb[64];
  int tid = threadIdx.x;              // 256
  int base = blockIdx.x * 1024;
  if (tid < 64) {
    cnt[tid] = 0;
    int node = tid << 10;
    rpb[tid] = row_ptr[node < n ? node : n];
  }
  __syncthreads();
  int b[4], lp[4], sv[4], dl[4];
#pragma unroll
  for (int j = 0; j < 4; ++j) {
    int e = base + tid * 4 + j;
    if (e < E) {
      sv[j] = src[e];
      int d = dst[e];
      b[j] = d >> 10;
      dl[j] = d & 1023;
      lp[j] = atomicAdd(&cnt[b[j]], 1);
    } else {
      b[j] = -1;
    }
  }
  __syncthreads();
  if (tid < 64) {
    int c = cnt[tid];
    gbase[tid] = (c > 0) ? atomicAdd(&bucket_fill[tid], c) : 0;
  }
  __syncthreads();
#pragma unroll
  for (int j = 0; j < 4; ++j) {
    if (b[j] >= 0) {
      int pos = rpb[b[j]] + gbase[b[j]] + lp[j];
      stage[pos] = (unsigned)sv[j] | ((unsigned)dl[j] << 16);
    }
  }
}

// Phase B: one block per bucket; scatter within the bucket's ~32KB csr window
// (stays in one XCD's L2). LDS row-pointer window + LDS fill counters.
__global__ void local_fill_kernel(const unsigned* __restrict__ stage,
                                  const int* __restrict__ row_ptr,
                                  unsigned short* __restrict__ csr_src, int n) {
  __shared__ int rp[1024];
  __shared__ int lf[1024];
  int b = blockIdx.x;
  int node0 = b << 10;
  int nn = n - node0; if (nn > 1024) nn = 1024;
  int tid = threadIdx.x;              // 1024
  if (tid < nn) { rp[tid] = row_ptr[node0 + tid]; lf[tid] = 0; }
  __syncthreads();
  int ebeg = row_ptr[node0];
  int eend = row_ptr[node0 + nn];
  for (int i = ebeg + tid; i < eend; i += 1024) {
    unsigned p = stage[i];
    int dl = p >> 16;
    int s = p & 0xFFFF;
    int pos = rp[dl] + atomicAdd(&lf[dl], 1);
    csr_src[pos] = (unsigned short)s;
  }
}

// ---------- fused per-step kernel (R12 config: best measured, 57.8us) ----------

// elementwise GRU epilogue over one 16-row tile staged in padded LDS planes
__device__ __forceinline__ void gru_epilogue(const float* lds,
                                             const _Float16* __restrict__ h,
                                             _Float16* __restrict__ hout,
                                             const int* __restrict__ row_ptr,
                                             const float* __restrict__ bxe,
                                             const float* __restrict__ bih,
                                             const float* __restrict__ bhh,
                                             int base_row, int tid) {
#pragma unroll
  for (int j = 0; j < 4; ++j) {
    int e = tid + j * 384;
    int row = e / D;
    int col = e - row * D;
    int grow = base_row + row;
    int a = row * PLS + col;
    float degf = (float)(row_ptr[grow + 1] - row_ptr[grow]);
    float R  = lds[a] + lds[PLANE + a];
    float Z  = lds[2 * PLANE + a] + lds[3 * PLANE + a];
    float XN = lds[4 * PLANE + a];
    float HN = lds[5 * PLANE + a];
    float rg = 1.0f / (1.0f + __expf(-(R + bih[col] + bhh[col] + degf * bxe[col])));
    float zg = 1.0f / (1.0f + __expf(-(Z + bih[D + col] + bhh[D + col] + degf * bxe[D + col])));
    float ng = tanhf(XN + bih[2 * D + col] + degf * bxe[2 * D + col] + rg * (HN + bhh[2 * D + col]));
    float hv = (float)h[(size_t)grow * D + col];
    hout[(size_t)grow * D + col] = (_Float16)((1.0f - zg) * ng + zg * hv);
  }
}

// Fused aggregate + GRU. Block = 32 rows, 6 waves (384 threads).
// LDS: 6 padded planes (37.2 KB); s-tile ALIASES planes 4/5.
__global__ __launch_bounds__(384) void gru_fused_kernel(
    const _Float16* __restrict__ h, _Float16* __restrict__ hout,
    const int* __restrict__ row_ptr, const unsigned short* __restrict__ csr_src,
    const _Float16* __restrict__ WxF, const _Float16* __restrict__ WhhF,
    const float* __restrict__ bxe, const float* __restrict__ bih,
    const float* __restrict__ bhh, int n) {
  __shared__ float lds[6 * PLANE];                    // 37.2 KB total
  _Float16* sl = (_Float16*)&lds[4 * PLANE];          // s tile aliases planes 4/5
  int r0 = blockIdx.x << 5;   // 32 rows per block
  int tid = threadIdx.x;
  int w = tid >> 6;
  int lane = tid & 63;

  // ---- phase 1: gather (12 threads/row, one f16x8 chunk each; 8-deep MLP) ----
  {
    int row = tid / 12;        // 0..31
    int part = tid - row * 12; // chunk of 8 fp16
    int grow = r0 + row;
    float acc[8];
#pragma unroll
    for (int j = 0; j < 8; ++j) acc[j] = 0.f;
    if (grow < n) {
      int beg = row_ptr[grow], end = row_ptr[grow + 1];
      const _Float16* hp = h + (size_t)part * 8;
      int e = beg;
      for (; e + 7 < end; e += 8) {
        f16x8 v0 = *(const f16x8*)(hp + (size_t)csr_src[e] * D);
        f16x8 v1 = *(const f16x8*)(hp + (size_t)csr_src[e + 1] * D);
        f16x8 v2 = *(const f16x8*)(hp + (size_t)csr_src[e + 2] * D);
        f16x8 v3 = *(const f16x8*)(hp + (size_t)csr_src[e + 3] * D);
        f16x8 v4 = *(const f16x8*)(hp + (size_t)csr_src[e + 4] * D);
        f16x8 v5 = *(const f16x8*)(hp + (size_t)csr_src[e + 5] * D);
        f16x8 v6 = *(const f16x8*)(hp + (size_t)csr_src[e + 6] * D);
        f16x8 v7 = *(const f16x8*)(hp + (size_t)csr_src[e + 7] * D);
#pragma unroll
        for (int j = 0; j < 8; ++j)
          acc[j] += (((float)v0[j] + (float)v1[j]) + ((float)v2[j] + (float)v3[j])) +
                    (((float)v4[j] + (float)v5[j]) + ((float)v6[j] + (float)v7[j]));
      }
      if (e + 3 < end) {
        f16x8 v0 = *(const f16x8*)(hp + (size_t)csr_src[e] * D);
        f16x8 v1 = *(const f16x8*)(hp + (size_t)csr_src[e + 1] * D);
        f16x8 v2 = *(const f16x8*)(hp + (size_t)csr_src[e + 2] * D);
        f16x8 v3 = *(const f16x8*)(hp + (size_t)csr_src[e + 3] * D);
#pragma unroll
        for (int j = 0; j < 8; ++j)
          acc[j] += ((float)v0[j] + (float)v1[j]) + ((float)v2[j] + (float)v3[j]);
        e += 4;
      }
      for (; e < end; ++e) {
        f16x8 v = *(const f16x8*)(hp + (size_t)csr_src[e] * D);
#pragma unroll
        for (int j = 0; j < 8; ++j) acc[j] += (float)v[j];
      }
    }
    f16x8 o;
#pragma unroll
    for (int j = 0; j < 8; ++j) o[j] = (_Float16)acc[j];
    *(f16x8*)&sl[row * SLP + part * 8] = o;
  }
  __syncthreads();

  // ---- phase 2: A-fragment loads ----
  const int opS = (w < 3) ? 1 : 0;
  const _Float16* WF = opS ? WxF : WhhF;
  const int wg = opS ? w : (w - 3);        // 0=R, 1=Z, 2=N
  const int t0 = wg * 6;                   // col-tiles t0..t0+5
  const int plane = wg * 2 + (opS ? 0 : 1);

  f16x8 a0[3], a1[3];
  if (opS) {
#pragma unroll
    for (int kc = 0; kc < 3; ++kc) {
      int k0 = kc * 32 + ((lane >> 4) << 3);
      a0[kc] = *(const f16x8*)&sl[(lane & 15) * SLP + k0];
      a1[kc] = *(const f16x8*)&sl[(16 + (lane & 15)) * SLP + k0];
    }
  } else {
#pragma unroll
    for (int kc = 0; kc < 3; ++kc) {
      a0[kc] = load_a_frag(h, r0, lane, kc);
      a1[kc] = load_a_frag(h, r0 + 16, lane, kc);
    }
  }
  __syncthreads();   // sl fully read (in regs) before planes 4/5 are overwritten

  f32x4 acc0[6], acc1[6];
#pragma unroll
  for (int t = 0; t < 6; ++t) {
    acc0[t] = (f32x4){0.f, 0.f, 0.f, 0.f};
    acc1[t] = (f32x4){0.f, 0.f, 0.f, 0.f};
  }

#pragma unroll
  for (int ct = 0; ct < 6; ++ct)
#pragma unroll
    for (int kc = 0; kc < 3; ++kc) {
      f16x8 b = load_b_swz(WF, t0 + ct, kc, lane);
      acc0[ct] = __builtin_amdgcn_mfma_f32_16x16x32_f16(a0[kc], b, acc0[ct], 0, 0, 0);
      acc1[ct] = __builtin_amdgcn_mfma_f32_16x16x32_f16(a1[kc], b, acc1[ct], 0, 0, 0);
    }

  // ---- phase 3: epilogues (C/D layout: col=lane&15, row=(lane>>4)*4+q) ----
  int col_l = lane & 15;
  int rq = (lane >> 4) << 2;
#pragma unroll
  for (int ct = 0; ct < 6; ++ct)
#pragma unroll
    for (int q = 0; q < 4; ++q)
      lds[plane * PLANE + (rq + q) * PLS + ct * 16 + col_l] = acc0[ct][q];
  __syncthreads();
  gru_epilogue(lds, h, hout, row_ptr, bxe, bih, bhh, r0, tid);
  __syncthreads();
  if (r0 + 16 < n) {
#pragma unroll
    for (int ct = 0; ct < 6; ++ct)
#pragma unroll
      for (int q = 0; q < 4; ++q)
        lds[plane * PLANE + (rq + q) * PLS + ct * 16 + col_l] = acc1[ct][q];
    __syncthreads();
    gru_epilogue(lds, h, hout, row_ptr, bxe, bih, bhh, r0 + 16, tid);
  }
}

// logits[i,c] = sum_k elu(h[i,k]) * Wfc[c,k] + bfc[c]
__global__ void head_kernel(const _Float16* __restrict__ h,
                            const float* __restrict__ Wfc,
                            const float* __restrict__ bfc,
                            float* __restrict__ out,
                            int n, int C) {
  int idx = blockIdx.x * blockDim.x + threadIdx.x;
  if (idx >= n * C) return;
  int i = idx / C;
  int c = idx - i * C;
  const _Float16* hr = h + (size_t)i * D;
  const float* wr = Wfc + (size_t)c * D;
  float acc = bfc[c];
#pragma unroll 8
  for (int k = 0; k < D; ++k) {
    float hv = (float)hr[k];
    float e = hv > 0.0f ? hv : (__expf(hv) - 1.0f);
    acc += e * wr[k];
  }
  out[idx] = acc;
}

extern "C" void kernel_launch(void* const* d_in, const int* in_sizes, int n_in,
                              void* d_out, int out_size, void* d_ws, size_t ws_size,
                              hipStream_t stream) {
  const float* x    = (const float*)d_in[0];
  const int*   src  = (const int*)d_in[1];
  const int*   dst  = (const int*)d_in[2];
  const float* W_e  = (const float*)d_in[3];
  const float* b_e  = (const float*)d_in[4];
  const float* W_ih = (const float*)d_in[5];
  const float* W_hh = (const float*)d_in[6];
  const float* b_ih = (const float*)d_in[7];
  const float* b_hh = (const float*)d_in[8];
  const float* W_fc = (const float*)d_in[9];
  const float* b_fc = (const float*)d_in[10];

  const int n = in_sizes[0] / D;   // 50000
  const int E = in_sizes[1];       // 800000
  const int C = out_size / n;      // 10

  // ws layout (fp16 state):
  _Float16* hA = (_Float16*)d_ws;                 // n*D fp16
  _Float16* hB = hA + (size_t)n * D;              // n*D fp16
  float* Wx    = (float*)(hB + (size_t)n * D);    // G3*D fp32 temp
  _Float16* WxF  = (_Float16*)(Wx + (size_t)G3 * D);  // G3*D fp16 swizzled
  _Float16* WhhF = WxF + (size_t)G3 * D;
  float* bxe   = (float*)(WhhF + (size_t)G3 * D); // G3 fp32
  int* counts  = (int*)(bxe + G3);                // n
  int* bucket_fill = counts + n;                  // 64 (reuses old fillc slot)
  int* row_ptr = bucket_fill + n;                 // n+1
  unsigned short* csr_src = (unsigned short*)(row_ptr + (n + 1));  // E u16
  int* blk_sums = (int*)(csr_src + E);            // <=64
  int* blk_off  = blk_sums + 64;                  // <=64
  unsigned* stage = (unsigned*)(blk_off + 64);    // E u32 packed (src | dl<<16)

  const int threads = 256;
  const int nb = (n + SCAN_BLK - 1) / SCAN_BLK;   // 49 scan blocks
  const int NB = (n + 1023) >> 10;                // 49 dst buckets

  (void)hipMemsetAsync(counts, 0, (size_t)2 * n * sizeof(int), stream);  // counts + bucket_fill
  hist_kernel<<<(E + threads - 1) / threads, threads, 0, stream>>>(dst, counts, E);
  partial_sum_kernel<<<nb, 256, 0, stream>>>(counts, blk_sums, n);
  scan_offsets_kernel<<<1, 64, 0, stream>>>(blk_sums, blk_off, row_ptr, nb, n);
  block_scan_kernel<<<nb, 256, 0, stream>>>(counts, blk_off, row_ptr, n);
  route_kernel<<<(E + 1023) / 1024, 256, 0, stream>>>(src, dst, row_ptr,
                                                      bucket_fill, stage, E, n);
  local_fill_kernel<<<NB, 1024, 0, stream>>>(stage, row_ptr, csr_src, n);
  compute_wx_kernel<<<(G3 * D + G3 + threads - 1) / threads, threads, 0, stream>>>(
      W_ih, W_e, b_e, Wx, bxe);
  swizzle_f16_kernel<<<(2 * NT * 3 * 64 + threads - 1) / threads, threads, 0, stream>>>(
      Wx, W_hh, WxF, WhhF);
  convert_x_kernel<<<((n * D / 4) + threads - 1) / threads, threads, 0, stream>>>(
      x, hA, n * D / 4);

  const int gridG = (n + 31) / 32;   // 32 rows per block

  const _Float16* hcur = hA;
  _Float16* hnext = hB;
  for (int step = 0; step < NSTEPS; ++step) {
    gru_fused_kernel<<<gridG, 384, 0, stream>>>(hcur, hnext, row_ptr, csr_src,
                                                WxF, WhhF, bxe, b_ih, b_hh, n);
    const _Float16* t = hcur; hcur = hnext; hnext = (_Float16*)t;
  }

  const int gridH = (n * C + threads - 1) / threads;
  head_kernel<<<gridH, threads, 0, stream>>>(hcur, W_fc, b_fc, (float*)d_out, n, C);
}